// Round 8
// baseline (1221.016 us; speedup 1.0000x reference)
//
#include <hip/hip_runtime.h>

#define NTOK 49
#define CDIM 384
#define HEADS 12
#define HD 32
#define NWIN 64
#define NQKV 1152
#define SCALE 0.17677669529663687f  // 32^-0.5

typedef __attribute__((ext_vector_type(8))) __bf16 bf16x8;
typedef __attribute__((ext_vector_type(4))) float f32x4;

// workspace offsets (bytes), all 256-aligned
#define OFF_WQKVT   0ull                 // 1152*384 bf16 = 884736
#define OFF_WOUTT   884736ull            // 384*384 bf16  = 294912
#define OFF_ADDEND  1179648ull           // 64*12*49*49 f32 = 7375872
#define OFF_QKVB    8555520ull           // 200704*1152 bf16 = 462422016
#define OFF_XB      470977536ull         // 200704*384 bf16 = 154140672 (dead after gemm_qkv)
// total ~625.1 MB

__device__ __forceinline__ void async_copy16(__bf16* lds_dst, const __bf16* g_src) {
    __builtin_amdgcn_global_load_lds(
        (const __attribute__((address_space(1))) void*)g_src,
        (__attribute__((address_space(3))) void*)lds_dst,
        16, 0, 0);
}

// ---------------- prep kernels ----------------

__global__ void prep_weights(const float* __restrict__ Wqkv, const float* __restrict__ Wout,
                             __bf16* __restrict__ WqkvT, __bf16* __restrict__ WoutT) {
    int idx = blockIdx.x * 256 + threadIdx.x;
    if (idx < NQKV * CDIM) {
        int n = idx / CDIM, k = idx % CDIM;
        WqkvT[idx] = (__bf16)Wqkv[(size_t)k * NQKV + n];
    }
    if (idx < CDIM * CDIM) {
        int n = idx / CDIM, k = idx % CDIM;
        WoutT[idx] = (__bf16)Wout[(size_t)k * CDIM + n];
    }
}

__global__ void prep_addend(const float* __restrict__ rpb, const int* __restrict__ rel,
                            const float* __restrict__ mask, float* __restrict__ addend) {
    int idx = blockIdx.x * 256 + threadIdx.x;
    if (idx >= NWIN * HEADS * NTOK * NTOK) return;
    int mn = idx % (NTOK * NTOK);
    int h  = (idx / (NTOK * NTOK)) % HEADS;
    int w  = idx / (NTOK * NTOK * HEADS);
    addend[idx] = rpb[rel[mn] * HEADS + h] + mask[(size_t)w * NTOK * NTOK + mn];
}

// x fp32 -> bf16, streaming (8 elems / thread / iter)
__global__ __launch_bounds__(256) void prep_xb(const float* __restrict__ x,
                                               __bf16* __restrict__ xb, int total8) {
    int stride = gridDim.x * 256;
    for (int i = blockIdx.x * 256 + threadIdx.x; i < total8; i += stride) {
        float4 a = reinterpret_cast<const float4*>(x)[i * 2];
        float4 b = reinterpret_cast<const float4*>(x)[i * 2 + 1];
        union { __bf16 h[8]; uint4 u; } t;
        t.h[0] = (__bf16)a.x; t.h[1] = (__bf16)a.y; t.h[2] = (__bf16)a.z; t.h[3] = (__bf16)a.w;
        t.h[4] = (__bf16)b.x; t.h[5] = (__bf16)b.y; t.h[6] = (__bf16)b.z; t.h[7] = (__bf16)b.w;
        reinterpret_cast<uint4*>(xb)[i] = t.u;
    }
}

// ---------------- K1: qkv GEMM, m97 structure + XCD swizzle (unchanged) ----------------

__global__ __launch_bounds__(256, 3) void gemm_qkv(
    const __bf16* __restrict__ xb, const __bf16* __restrict__ WqkvT,
    const float* __restrict__ bqkv, __bf16* __restrict__ qkvb)
{
    __shared__ __attribute__((aligned(16))) __bf16 smem[16384];  // A [0,8192), B [8192,16384); C overlays
    __bf16* As = smem;
    __bf16* Bs = smem + 8192;

    // bijective XCD-chunk swizzle: nwg = 14112 = 8 * 1764
    const int cpx  = 14112 >> 3;                     // 1764
    const int lid  = (blockIdx.x & 7) * cpx + (blockIdx.x >> 3);
    const int mblk = lid / 9, nblk = lid % 9;
    const int n0  = nblk * 128;
    const int bm0 = mblk * 128;

    const int tid = threadIdx.x;
    const int wave = tid >> 6, lane = tid & 63;
    const int l15 = lane & 15, l4 = lane >> 4;
    const int wr = wave >> 1, wc = wave & 1;

    f32x4 acc[4][4] = {};

    for (int k0 = 0; k0 < CDIM; k0 += 64) {
#pragma unroll
        for (int j = 0; j < 4; ++j) {
            int c = wave * 4 + j;
            int mt = c >> 1, kk = c & 1;
            const __bf16* sa = xb + (size_t)(bm0 + mt * 16 + l15) * CDIM + k0 + kk * 32 + l4 * 8;
            async_copy16(&As[c * 512], sa);
            const __bf16* sb = WqkvT + (size_t)(n0 + mt * 16 + l15) * CDIM + k0 + kk * 32 + l4 * 8;
            async_copy16(&Bs[c * 512], sb);
        }
        __syncthreads();

#pragma unroll
        for (int kk = 0; kk < 2; ++kk) {
            bf16x8 af[4], bf[4];
#pragma unroll
            for (int mi = 0; mi < 4; ++mi)
                af[mi] = *reinterpret_cast<const bf16x8*>(&As[((wr * 4 + mi) * 2 + kk) * 512 + lane * 8]);
#pragma unroll
            for (int ni = 0; ni < 4; ++ni)
                bf[ni] = *reinterpret_cast<const bf16x8*>(&Bs[((wc * 4 + ni) * 2 + kk) * 512 + lane * 8]);
#pragma unroll
            for (int mi = 0; mi < 4; ++mi)
#pragma unroll
                for (int ni = 0; ni < 4; ++ni)
                    acc[mi][ni] = __builtin_amdgcn_mfma_f32_16x16x32_bf16(af[mi], bf[ni], acc[mi][ni], 0, 0, 0);
        }
        __syncthreads();
    }

    const float scl = (n0 < CDIM) ? SCALE : 1.0f;
    float bias[4];
#pragma unroll
    for (int ni = 0; ni < 4; ++ni)
        bias[ni] = bqkv[n0 + wc * 64 + ni * 16 + l15];

    __bf16* Cs = smem;   // [128][128] bf16, byte ^= ((row>>2)&3)<<5
#pragma unroll
    for (int mi = 0; mi < 4; ++mi)
#pragma unroll
        for (int ni = 0; ni < 4; ++ni)
#pragma unroll
            for (int r = 0; r < 4; ++r) {
                int row = wr * 64 + mi * 16 + l4 * 4 + r;
                int col = wc * 64 + ni * 16 + l15;
                int byte = (row * 256 + col * 2) ^ (((row >> 2) & 3) << 5);
                *reinterpret_cast<__bf16*>(reinterpret_cast<char*>(Cs) + byte) =
                    (__bf16)((acc[mi][ni][r] + bias[ni]) * scl);
            }
    __syncthreads();

#pragma unroll
    for (int it = 0; it < 8; ++it) {
        int idx = it * 4096 + tid * 16;
        int row = idx >> 8, bcol = idx & 255;
        int sb = (row * 256 + bcol) ^ (((row >> 2) & 3) << 5);
        uint4 v = *reinterpret_cast<const uint4*>(reinterpret_cast<const char*>(Cs) + sb);
        *reinterpret_cast<uint4*>(reinterpret_cast<char*>(&qkvb[(size_t)(bm0 + row) * NQKV + n0]) + bcol) = v;
    }
}

// ---------------- K2: fused attention + out-projection ----------------
// grid B: one block per window, 256 thr = 4 waves.
// Phase 1: wave w does heads {w, 4+w, 8+w} sequentially (proven attn body);
//   o-fragments written straight into fragment-linear LDS tile ao (kb == h).
// Phase 2 (after 1 barrier): proven out_proj loop reads ao, writes fp32 out rows b*49..+48.

__global__ __launch_bounds__(256) void attn_oproj(
    const __bf16* __restrict__ qkvb, const float* __restrict__ addend,
    const __bf16* __restrict__ WoutT, const float* __restrict__ bout,
    float* __restrict__ out)
{
    __shared__ __attribute__((aligned(16))) __bf16 ao[4 * 12 * 512];  // frag-linear [mt][kb][slot][8], slot=lp^(kb&7)
    __shared__ __attribute__((aligned(16))) __bf16 ps[4][2][64][8];   // [wave][kb][lane][8]
    const int b = blockIdx.x;
    const int tid = threadIdx.x;
    const int wave = tid >> 6, lane = tid & 63;
    const int l15 = lane & 15, l4 = lane >> 4;
    const int w = b & (NWIN - 1);

    const __bf16* base = qkvb + (size_t)b * NTOK * NQKV;

    for (int hi = 0; hi < 3; ++hi) {
        const int h = hi * 4 + wave;

        bf16x8 kf[4];
#pragma unroll
        for (int nt = 0; nt < 4; ++nt)
            kf[nt] = *reinterpret_cast<const bf16x8*>(base + (size_t)(nt * 16 + l15) * NQKV + CDIM + h * HD + l4 * 8);

        bf16x8 vf[2][2];
#pragma unroll
        for (int dt = 0; dt < 2; ++dt)
#pragma unroll
            for (int kb = 0; kb < 2; ++kb)
#pragma unroll
                for (int j = 0; j < 8; ++j) {
                    int tok = kb * 32 + l4 * 8 + j;
                    vf[dt][kb][j] = base[(size_t)tok * NQKV + 2 * CDIM + h * HD + dt * 16 + l15];
                }

        const float* add_h = addend + (size_t)(w * HEADS + h) * (NTOK * NTOK);

        for (int mt = 0; mt < 4; ++mt) {
            bf16x8 qf = *reinterpret_cast<const bf16x8*>(base + (size_t)(mt * 16 + l15) * NQKV + h * HD + l4 * 8);
            f32x4 s[4];
#pragma unroll
            for (int nt = 0; nt < 4; ++nt) {
                f32x4 z = {};
                s[nt] = __builtin_amdgcn_mfma_f32_16x16x32_bf16(qf, kf[nt], z, 0, 0, 0);
            }

#pragma unroll
            for (int r = 0; r < 4; ++r) {
                int m = mt * 16 + l4 * 4 + r;
                float vals[4];
#pragma unroll
                for (int nt = 0; nt < 4; ++nt) {
                    int n = nt * 16 + l15;
                    float sv = s[nt][r];
                    if (n < NTOK) {
                        if (m < NTOK) sv += add_h[m * NTOK + n];
                    } else {
                        sv = -1e30f;
                    }
                    vals[nt] = sv;
                }
                float mx = fmaxf(fmaxf(vals[0], vals[1]), fmaxf(vals[2], vals[3]));
                mx = fmaxf(mx, __shfl_xor(mx, 1));
                mx = fmaxf(mx, __shfl_xor(mx, 2));
                mx = fmaxf(mx, __shfl_xor(mx, 4));
                mx = fmaxf(mx, __shfl_xor(mx, 8));
                float e0 = __expf(vals[0] - mx);
                float e1 = __expf(vals[1] - mx);
                float e2 = __expf(vals[2] - mx);
                float e3 = __expf(vals[3] - mx);
                float sum = (e0 + e1) + (e2 + e3);
                sum += __shfl_xor(sum, 1);
                sum += __shfl_xor(sum, 2);
                sum += __shfl_xor(sum, 4);
                sum += __shfl_xor(sum, 8);
                float inv = 1.0f / sum;
                float ev[4] = {e0, e1, e2, e3};
#pragma unroll
                for (int nt = 0; nt < 4; ++nt) {
                    int lp = (l4 * 4 + r) + 16 * ((nt & 1) * 2 + (l15 >> 3));
                    ps[wave][nt >> 1][lp][l15 & 7] = (__bf16)(ev[nt] * inv);
                }
            }

            f32x4 o[2] = {};
#pragma unroll
            for (int kb = 0; kb < 2; ++kb) {
                bf16x8 ap = *reinterpret_cast<const bf16x8*>(&ps[wave][kb][lane][0]);
#pragma unroll
                for (int dt = 0; dt < 2; ++dt)
                    o[dt] = __builtin_amdgcn_mfma_f32_16x16x32_bf16(ap, vf[dt][kb], o[dt], 0, 0, 0);
            }
            // write o-frags into fragment-linear ao tile: col = h*32+dt*16+l15 -> kb = h
#pragma unroll
            for (int dt = 0; dt < 2; ++dt) {
#pragma unroll
                for (int r = 0; r < 4; ++r) {
                    int lp = (l4 * 4 + r) + 16 * (dt * 2 + (l15 >> 3));
                    int slot = lp ^ (h & 7);
                    ao[((mt * 12 + h) * 64 + slot) * 8 + (l15 & 7)] = (__bf16)o[dt][r];
                }
            }
        }
    }
    __syncthreads();

    // ---- phase 2: out projection from LDS ao ----
    f32x4 acc[6][4] = {};
    for (int kb = 0; kb < 12; ++kb) {
        int slot = lane ^ (kb & 7);
        bf16x8 af[4];
#pragma unroll
        for (int mt = 0; mt < 4; ++mt)
            af[mt] = *reinterpret_cast<const bf16x8*>(&ao[((mt * 12 + kb) * 64 + slot) * 8]);
#pragma unroll
        for (int j = 0; j < 6; ++j) {
            int col = (wave * 6 + j) * 16 + l15;
            bf16x8 bf = *reinterpret_cast<const bf16x8*>(WoutT + (size_t)col * CDIM + kb * 32 + l4 * 8);
#pragma unroll
            for (int mt = 0; mt < 4; ++mt)
                acc[j][mt] = __builtin_amdgcn_mfma_f32_16x16x32_bf16(af[mt], bf, acc[j][mt], 0, 0, 0);
        }
    }
#pragma unroll
    for (int j = 0; j < 6; ++j) {
        int col = (wave * 6 + j) * 16 + l15;
        float bias = bout[col];
#pragma unroll
        for (int mt = 0; mt < 4; ++mt) {
#pragma unroll
            for (int r = 0; r < 4; ++r) {
                int tok = mt * 16 + l4 * 4 + r;
                if (tok < NTOK)
                    out[((size_t)b * NTOK + tok) * CDIM + col] = acc[j][mt][r] + bias;
            }
        }
    }
}

// ---------------- launch ----------------

extern "C" void kernel_launch(void* const* d_in, const int* in_sizes, int n_in,
                              void* d_out, int out_size, void* d_ws, size_t ws_size,
                              hipStream_t stream) {
    (void)n_in; (void)out_size; (void)ws_size;
    const float* x    = (const float*)d_in[0];
    const float* mask = (const float*)d_in[1];
    const float* Wqkv = (const float*)d_in[2];
    const float* bqkv = (const float*)d_in[3];
    const float* Wout = (const float*)d_in[4];
    const float* bout = (const float*)d_in[5];
    const float* rpb  = (const float*)d_in[6];
    const int*   rel  = (const int*)d_in[7];

    const int B = in_sizes[0] / (NTOK * CDIM);   // 4096
    const int M = B * NTOK;                      // 200704

    char* ws = (char*)d_ws;
    __bf16* WqkvT   = (__bf16*)(ws + OFF_WQKVT);
    __bf16* WoutT   = (__bf16*)(ws + OFF_WOUTT);
    float*  addend  = (float*)(ws + OFF_ADDEND);
    __bf16* qkvb    = (__bf16*)(ws + OFF_QKVB);
    __bf16* xb      = (__bf16*)(ws + OFF_XB);
    float*  out     = (float*)d_out;

    prep_weights<<<(NQKV * CDIM + 255) / 256, 256, 0, stream>>>(Wqkv, Wout, WqkvT, WoutT);
    prep_addend<<<(NWIN * HEADS * NTOK * NTOK + 255) / 256, 256, 0, stream>>>(rpb, rel, mask, addend);
    prep_xb<<<2048, 256, 0, stream>>>(x, xb, M * CDIM / 8);
    gemm_qkv<<<(M / 128) * (NQKV / 128), 256, 0, stream>>>(xb, WqkvT, bqkv, qkvb);
    attn_oproj<<<B, 256, 0, stream>>>(qkvb, addend, WoutT, bout, out);
}

// Round 9
// 1120.697 us; speedup vs baseline: 1.0895x; 1.0895x over previous
//
#include <hip/hip_runtime.h>

#define NTOK 49
#define CDIM 384
#define HEADS 12
#define HD 32
#define NWIN 64
#define NQKV 1152
#define SCALE 0.17677669529663687f  // 32^-0.5

typedef __attribute__((ext_vector_type(8))) __bf16 bf16x8;
typedef __attribute__((ext_vector_type(4))) float f32x4;

// workspace offsets (bytes), all 256-aligned
#define OFF_WQKVT   0ull                 // 1152*384 bf16 = 884736
#define OFF_WOUTT   884736ull            // 384*384 bf16  = 294912
#define OFF_ADDEND  1179648ull           // 64*12*49*49 f32 = 7375872
#define OFF_QKVB    8555520ull           // 200704*1152 bf16 = 462422016
#define OFF_XB      470977536ull         // 200704*384 bf16 = 154140672 (dead after gemm_qkv)
// total ~625.1 MB

__device__ __forceinline__ void async_copy16(__bf16* lds_dst, const __bf16* g_src) {
    __builtin_amdgcn_global_load_lds(
        (const __attribute__((address_space(1))) void*)g_src,
        (__attribute__((address_space(3))) void*)lds_dst,
        16, 0, 0);
}

// ---------------- prep kernels ----------------

__global__ void prep_weights(const float* __restrict__ Wqkv, const float* __restrict__ Wout,
                             __bf16* __restrict__ WqkvT, __bf16* __restrict__ WoutT) {
    int idx = blockIdx.x * 256 + threadIdx.x;
    if (idx < NQKV * CDIM) {
        int n = idx / CDIM, k = idx % CDIM;
        WqkvT[idx] = (__bf16)Wqkv[(size_t)k * NQKV + n];
    }
    if (idx < CDIM * CDIM) {
        int n = idx / CDIM, k = idx % CDIM;
        WoutT[idx] = (__bf16)Wout[(size_t)k * CDIM + n];
    }
}

__global__ void prep_addend(const float* __restrict__ rpb, const int* __restrict__ rel,
                            const float* __restrict__ mask, float* __restrict__ addend) {
    int idx = blockIdx.x * 256 + threadIdx.x;
    if (idx >= NWIN * HEADS * NTOK * NTOK) return;
    int mn = idx % (NTOK * NTOK);
    int h  = (idx / (NTOK * NTOK)) % HEADS;
    int w  = idx / (NTOK * NTOK * HEADS);
    addend[idx] = rpb[rel[mn] * HEADS + h] + mask[(size_t)w * NTOK * NTOK + mn];
}

// x fp32 -> bf16, streaming (8 elems / thread / iter)
__global__ __launch_bounds__(256) void prep_xb(const float* __restrict__ x,
                                               __bf16* __restrict__ xb, int total8) {
    int stride = gridDim.x * 256;
    for (int i = blockIdx.x * 256 + threadIdx.x; i < total8; i += stride) {
        float4 a = reinterpret_cast<const float4*>(x)[i * 2];
        float4 b = reinterpret_cast<const float4*>(x)[i * 2 + 1];
        union { __bf16 h[8]; uint4 u; } t;
        t.h[0] = (__bf16)a.x; t.h[1] = (__bf16)a.y; t.h[2] = (__bf16)a.z; t.h[3] = (__bf16)a.w;
        t.h[4] = (__bf16)b.x; t.h[5] = (__bf16)b.y; t.h[6] = (__bf16)b.z; t.h[7] = (__bf16)b.w;
        reinterpret_cast<uint4*>(xb)[i] = t.u;
    }
}

// ---------------- K1: qkv GEMM, m97 structure + XCD swizzle (unchanged) ----------------

__global__ __launch_bounds__(256, 3) void gemm_qkv(
    const __bf16* __restrict__ xb, const __bf16* __restrict__ WqkvT,
    const float* __restrict__ bqkv, __bf16* __restrict__ qkvb)
{
    __shared__ __attribute__((aligned(16))) __bf16 smem[16384];  // A [0,8192), B [8192,16384); C overlays
    __bf16* As = smem;
    __bf16* Bs = smem + 8192;

    // bijective XCD-chunk swizzle: nwg = 14112 = 8 * 1764
    const int cpx  = 14112 >> 3;                     // 1764
    const int lid  = (blockIdx.x & 7) * cpx + (blockIdx.x >> 3);
    const int mblk = lid / 9, nblk = lid % 9;
    const int n0  = nblk * 128;
    const int bm0 = mblk * 128;

    const int tid = threadIdx.x;
    const int wave = tid >> 6, lane = tid & 63;
    const int l15 = lane & 15, l4 = lane >> 4;
    const int wr = wave >> 1, wc = wave & 1;

    f32x4 acc[4][4] = {};

    for (int k0 = 0; k0 < CDIM; k0 += 64) {
#pragma unroll
        for (int j = 0; j < 4; ++j) {
            int c = wave * 4 + j;
            int mt = c >> 1, kk = c & 1;
            const __bf16* sa = xb + (size_t)(bm0 + mt * 16 + l15) * CDIM + k0 + kk * 32 + l4 * 8;
            async_copy16(&As[c * 512], sa);
            const __bf16* sb = WqkvT + (size_t)(n0 + mt * 16 + l15) * CDIM + k0 + kk * 32 + l4 * 8;
            async_copy16(&Bs[c * 512], sb);
        }
        __syncthreads();

#pragma unroll
        for (int kk = 0; kk < 2; ++kk) {
            bf16x8 af[4], bf[4];
#pragma unroll
            for (int mi = 0; mi < 4; ++mi)
                af[mi] = *reinterpret_cast<const bf16x8*>(&As[((wr * 4 + mi) * 2 + kk) * 512 + lane * 8]);
#pragma unroll
            for (int ni = 0; ni < 4; ++ni)
                bf[ni] = *reinterpret_cast<const bf16x8*>(&Bs[((wc * 4 + ni) * 2 + kk) * 512 + lane * 8]);
#pragma unroll
            for (int mi = 0; mi < 4; ++mi)
#pragma unroll
                for (int ni = 0; ni < 4; ++ni)
                    acc[mi][ni] = __builtin_amdgcn_mfma_f32_16x16x32_bf16(af[mi], bf[ni], acc[mi][ni], 0, 0, 0);
        }
        __syncthreads();
    }

    const float scl = (n0 < CDIM) ? SCALE : 1.0f;
    float bias[4];
#pragma unroll
    for (int ni = 0; ni < 4; ++ni)
        bias[ni] = bqkv[n0 + wc * 64 + ni * 16 + l15];

    __bf16* Cs = smem;   // [128][128] bf16, byte ^= ((row>>2)&3)<<5
#pragma unroll
    for (int mi = 0; mi < 4; ++mi)
#pragma unroll
        for (int ni = 0; ni < 4; ++ni)
#pragma unroll
            for (int r = 0; r < 4; ++r) {
                int row = wr * 64 + mi * 16 + l4 * 4 + r;
                int col = wc * 64 + ni * 16 + l15;
                int byte = (row * 256 + col * 2) ^ (((row >> 2) & 3) << 5);
                *reinterpret_cast<__bf16*>(reinterpret_cast<char*>(Cs) + byte) =
                    (__bf16)((acc[mi][ni][r] + bias[ni]) * scl);
            }
    __syncthreads();

#pragma unroll
    for (int it = 0; it < 8; ++it) {
        int idx = it * 4096 + tid * 16;
        int row = idx >> 8, bcol = idx & 255;
        int sb = (row * 256 + bcol) ^ (((row >> 2) & 3) << 5);
        uint4 v = *reinterpret_cast<const uint4*>(reinterpret_cast<const char*>(Cs) + sb);
        *reinterpret_cast<uint4*>(reinterpret_cast<char*>(&qkvb[(size_t)(bm0 + row) * NQKV + n0]) + bcol) = v;
    }
}

// ---------------- K2: fused attention + out-projection (rebalanced) ----------------
// grid B: one block per window, 512 threads = 8 waves.
// Phase 1: 24 units = (head h, mt-half); unit u = wave*3+i, h = u>>1, mts = {(u&1)*2, (u&1)*2+1}.
//   Even 3 units/wave; o-frags written straight into fragment-linear LDS tile ao (kb == h).
// Phase 2 (1 barrier): out-proj, wave owns 3 n-tiles (acc[3][4] = 48 AGPR), writes fp32 out.
// __launch_bounds__(512,2): cap 256 unified regs -> 8 waves/CU guaranteed (LDS 64KB -> 1 block/CU).

__global__ __launch_bounds__(512, 2) void attn_oproj(
    const __bf16* __restrict__ qkvb, const float* __restrict__ addend,
    const __bf16* __restrict__ WoutT, const float* __restrict__ bout,
    float* __restrict__ out)
{
    __shared__ __attribute__((aligned(16))) __bf16 ao[4 * 12 * 512];  // frag-linear [mt][kb][slot][8], slot=lp^(kb&7)
    __shared__ __attribute__((aligned(16))) __bf16 ps[8][2][64][8];   // [wave][kb][lane][8]
    const int b = blockIdx.x;
    const int tid = threadIdx.x;
    const int wave = tid >> 6, lane = tid & 63;
    const int l15 = lane & 15, l4 = lane >> 4;
    const int w = b & (NWIN - 1);

    const __bf16* base = qkvb + (size_t)b * NTOK * NQKV;

    for (int i = 0; i < 3; ++i) {
        const int u = wave * 3 + i;       // 0..23
        const int h = u >> 1;             // head 0..11
        const int mh = (u & 1) * 2;       // mt base: 0 or 2

        bf16x8 kf[4];
#pragma unroll
        for (int nt = 0; nt < 4; ++nt)
            kf[nt] = *reinterpret_cast<const bf16x8*>(base + (size_t)(nt * 16 + l15) * NQKV + CDIM + h * HD + l4 * 8);

        bf16x8 vf[2][2];
#pragma unroll
        for (int dt = 0; dt < 2; ++dt)
#pragma unroll
            for (int kb = 0; kb < 2; ++kb)
#pragma unroll
                for (int j = 0; j < 8; ++j) {
                    int tok = kb * 32 + l4 * 8 + j;
                    vf[dt][kb][j] = base[(size_t)tok * NQKV + 2 * CDIM + h * HD + dt * 16 + l15];
                }

        const float* add_h = addend + (size_t)(w * HEADS + h) * (NTOK * NTOK);

#pragma unroll
        for (int mi = 0; mi < 2; ++mi) {
            const int mt = mh + mi;
            bf16x8 qf = *reinterpret_cast<const bf16x8*>(base + (size_t)(mt * 16 + l15) * NQKV + h * HD + l4 * 8);
            f32x4 s[4];
#pragma unroll
            for (int nt = 0; nt < 4; ++nt) {
                f32x4 z = {};
                s[nt] = __builtin_amdgcn_mfma_f32_16x16x32_bf16(qf, kf[nt], z, 0, 0, 0);
            }

#pragma unroll
            for (int r = 0; r < 4; ++r) {
                int m = mt * 16 + l4 * 4 + r;
                float vals[4];
#pragma unroll
                for (int nt = 0; nt < 4; ++nt) {
                    int n = nt * 16 + l15;
                    float sv = s[nt][r];
                    if (n < NTOK) {
                        if (m < NTOK) sv += add_h[m * NTOK + n];
                    } else {
                        sv = -1e30f;
                    }
                    vals[nt] = sv;
                }
                float mx = fmaxf(fmaxf(vals[0], vals[1]), fmaxf(vals[2], vals[3]));
                mx = fmaxf(mx, __shfl_xor(mx, 1));
                mx = fmaxf(mx, __shfl_xor(mx, 2));
                mx = fmaxf(mx, __shfl_xor(mx, 4));
                mx = fmaxf(mx, __shfl_xor(mx, 8));
                float e0 = __expf(vals[0] - mx);
                float e1 = __expf(vals[1] - mx);
                float e2 = __expf(vals[2] - mx);
                float e3 = __expf(vals[3] - mx);
                float sum = (e0 + e1) + (e2 + e3);
                sum += __shfl_xor(sum, 1);
                sum += __shfl_xor(sum, 2);
                sum += __shfl_xor(sum, 4);
                sum += __shfl_xor(sum, 8);
                float inv = 1.0f / sum;
                float ev[4] = {e0, e1, e2, e3};
#pragma unroll
                for (int nt = 0; nt < 4; ++nt) {
                    int lp = (l4 * 4 + r) + 16 * ((nt & 1) * 2 + (l15 >> 3));
                    ps[wave][nt >> 1][lp][l15 & 7] = (__bf16)(ev[nt] * inv);
                }
            }

            f32x4 o[2] = {};
#pragma unroll
            for (int kb = 0; kb < 2; ++kb) {
                bf16x8 ap = *reinterpret_cast<const bf16x8*>(&ps[wave][kb][lane][0]);
#pragma unroll
                for (int dt = 0; dt < 2; ++dt)
                    o[dt] = __builtin_amdgcn_mfma_f32_16x16x32_bf16(ap, vf[dt][kb], o[dt], 0, 0, 0);
            }
            // write o-frags into fragment-linear ao tile: col = h*32+dt*16+l15 -> kb = h
#pragma unroll
            for (int dt = 0; dt < 2; ++dt) {
#pragma unroll
                for (int r = 0; r < 4; ++r) {
                    int lp = (l4 * 4 + r) + 16 * (dt * 2 + (l15 >> 3));
                    int slot = lp ^ (h & 7);
                    ao[((mt * 12 + h) * 64 + slot) * 8 + (l15 & 7)] = (__bf16)o[dt][r];
                }
            }
        }
    }
    __syncthreads();

    // ---- phase 2: out projection from LDS ao; wave owns n-tiles wave*3..wave*3+2 ----
    f32x4 acc[3][4] = {};
    for (int kb = 0; kb < 12; ++kb) {
        int slot = lane ^ (kb & 7);
        bf16x8 af[4];
#pragma unroll
        for (int mt = 0; mt < 4; ++mt)
            af[mt] = *reinterpret_cast<const bf16x8*>(&ao[((mt * 12 + kb) * 64 + slot) * 8]);
#pragma unroll
        for (int j = 0; j < 3; ++j) {
            int col = (wave * 3 + j) * 16 + l15;
            bf16x8 bf = *reinterpret_cast<const bf16x8*>(WoutT + (size_t)col * CDIM + kb * 32 + l4 * 8);
#pragma unroll
            for (int mt = 0; mt < 4; ++mt)
                acc[j][mt] = __builtin_amdgcn_mfma_f32_16x16x32_bf16(af[mt], bf, acc[j][mt], 0, 0, 0);
        }
    }
#pragma unroll
    for (int j = 0; j < 3; ++j) {
        int col = (wave * 3 + j) * 16 + l15;
        float bias = bout[col];
#pragma unroll
        for (int mt = 0; mt < 4; ++mt) {
#pragma unroll
            for (int r = 0; r < 4; ++r) {
                int tok = mt * 16 + l4 * 4 + r;
                if (tok < NTOK)
                    out[((size_t)b * NTOK + tok) * CDIM + col] = acc[j][mt][r] + bias;
            }
        }
    }
}

// ---------------- launch ----------------

extern "C" void kernel_launch(void* const* d_in, const int* in_sizes, int n_in,
                              void* d_out, int out_size, void* d_ws, size_t ws_size,
                              hipStream_t stream) {
    (void)n_in; (void)out_size; (void)ws_size;
    const float* x    = (const float*)d_in[0];
    const float* mask = (const float*)d_in[1];
    const float* Wqkv = (const float*)d_in[2];
    const float* bqkv = (const float*)d_in[3];
    const float* Wout = (const float*)d_in[4];
    const float* bout = (const float*)d_in[5];
    const float* rpb  = (const float*)d_in[6];
    const int*   rel  = (const int*)d_in[7];

    const int B = in_sizes[0] / (NTOK * CDIM);   // 4096
    const int M = B * NTOK;                      // 200704

    char* ws = (char*)d_ws;
    __bf16* WqkvT   = (__bf16*)(ws + OFF_WQKVT);
    __bf16* WoutT   = (__bf16*)(ws + OFF_WOUTT);
    float*  addend  = (float*)(ws + OFF_ADDEND);
    __bf16* qkvb    = (__bf16*)(ws + OFF_QKVB);
    __bf16* xb      = (__bf16*)(ws + OFF_XB);
    float*  out     = (float*)d_out;

    prep_weights<<<(NQKV * CDIM + 255) / 256, 256, 0, stream>>>(Wqkv, Wout, WqkvT, WoutT);
    prep_addend<<<(NWIN * HEADS * NTOK * NTOK + 255) / 256, 256, 0, stream>>>(rpb, rel, mask, addend);
    prep_xb<<<2048, 256, 0, stream>>>(x, xb, M * CDIM / 8);
    gemm_qkv<<<(M / 128) * (NQKV / 128), 256, 0, stream>>>(xb, WqkvT, bqkv, qkvb);
    attn_oproj<<<B, 512, 0, stream>>>(qkvb, addend, WoutT, bout, out);
}

// Round 10
// 938.040 us; speedup vs baseline: 1.3017x; 1.1947x over previous
//
#include <hip/hip_runtime.h>

#define NTOK 49
#define CDIM 384
#define HEADS 12
#define HD 32
#define NWIN 64
#define NQKV 1152
#define SCALE 0.17677669529663687f  // 32^-0.5

typedef __attribute__((ext_vector_type(8))) __bf16 bf16x8;
typedef __attribute__((ext_vector_type(4))) float f32x4;

// workspace offsets (bytes), all 256-aligned
#define OFF_WQKVT   0ull                 // 1152*384 bf16 = 884736
#define OFF_WOUTT   884736ull            // 384*384 bf16  = 294912
#define OFF_ADDEND  1179648ull           // 64*12*49*49 f32 = 7375872
#define OFF_QKVB    8555520ull           // 200704*1152 bf16 = 462422016
#define OFF_ATTNOUT 470977536ull         // 200704*384 bf16 = 154140672
#define OFF_XB      OFF_ATTNOUT          // xb aliases attnout: xb dead before attn writes
// total ~625.1 MB

__device__ __forceinline__ void async_copy16(__bf16* lds_dst, const __bf16* g_src) {
    __builtin_amdgcn_global_load_lds(
        (const __attribute__((address_space(1))) void*)g_src,
        (__attribute__((address_space(3))) void*)lds_dst,
        16, 0, 0);
}

// ---------------- prep kernels ----------------

__global__ void prep_weights(const float* __restrict__ Wqkv, const float* __restrict__ Wout,
                             __bf16* __restrict__ WqkvT, __bf16* __restrict__ WoutT) {
    int idx = blockIdx.x * 256 + threadIdx.x;
    if (idx < NQKV * CDIM) {
        int n = idx / CDIM, k = idx % CDIM;
        WqkvT[idx] = (__bf16)Wqkv[(size_t)k * NQKV + n];
    }
    if (idx < CDIM * CDIM) {
        int n = idx / CDIM, k = idx % CDIM;
        WoutT[idx] = (__bf16)Wout[(size_t)k * CDIM + n];
    }
}

__global__ void prep_addend(const float* __restrict__ rpb, const int* __restrict__ rel,
                            const float* __restrict__ mask, float* __restrict__ addend) {
    int idx = blockIdx.x * 256 + threadIdx.x;
    if (idx >= NWIN * HEADS * NTOK * NTOK) return;
    int mn = idx % (NTOK * NTOK);
    int h  = (idx / (NTOK * NTOK)) % HEADS;
    int w  = idx / (NTOK * NTOK * HEADS);
    addend[idx] = rpb[rel[mn] * HEADS + h] + mask[(size_t)w * NTOK * NTOK + mn];
}

// x fp32 -> bf16, streaming (8 elems / thread / iter)
__global__ __launch_bounds__(256) void prep_xb(const float* __restrict__ x,
                                               __bf16* __restrict__ xb, int total8) {
    int stride = gridDim.x * 256;
    for (int i = blockIdx.x * 256 + threadIdx.x; i < total8; i += stride) {
        float4 a = reinterpret_cast<const float4*>(x)[i * 2];
        float4 b = reinterpret_cast<const float4*>(x)[i * 2 + 1];
        union { __bf16 h[8]; uint4 u; } t;
        t.h[0] = (__bf16)a.x; t.h[1] = (__bf16)a.y; t.h[2] = (__bf16)a.z; t.h[3] = (__bf16)a.w;
        t.h[4] = (__bf16)b.x; t.h[5] = (__bf16)b.y; t.h[6] = (__bf16)b.z; t.h[7] = (__bf16)b.w;
        reinterpret_cast<uint4*>(xb)[i] = t.u;
    }
}

// ---------------- K1: qkv GEMM, m97 structure + XCD swizzle (unchanged from r7) ----------------

__global__ __launch_bounds__(256, 3) void gemm_qkv(
    const __bf16* __restrict__ xb, const __bf16* __restrict__ WqkvT,
    const float* __restrict__ bqkv, __bf16* __restrict__ qkvb)
{
    __shared__ __attribute__((aligned(16))) __bf16 smem[16384];  // A [0,8192), B [8192,16384); C overlays
    __bf16* As = smem;
    __bf16* Bs = smem + 8192;

    // bijective XCD-chunk swizzle: nwg = 14112 = 8 * 1764
    const int cpx  = 14112 >> 3;                     // 1764
    const int lid  = (blockIdx.x & 7) * cpx + (blockIdx.x >> 3);
    const int mblk = lid / 9, nblk = lid % 9;
    const int n0  = nblk * 128;
    const int bm0 = mblk * 128;

    const int tid = threadIdx.x;
    const int wave = tid >> 6, lane = tid & 63;
    const int l15 = lane & 15, l4 = lane >> 4;
    const int wr = wave >> 1, wc = wave & 1;

    f32x4 acc[4][4] = {};

    for (int k0 = 0; k0 < CDIM; k0 += 64) {
#pragma unroll
        for (int j = 0; j < 4; ++j) {
            int c = wave * 4 + j;
            int mt = c >> 1, kk = c & 1;
            const __bf16* sa = xb + (size_t)(bm0 + mt * 16 + l15) * CDIM + k0 + kk * 32 + l4 * 8;
            async_copy16(&As[c * 512], sa);
            const __bf16* sb = WqkvT + (size_t)(n0 + mt * 16 + l15) * CDIM + k0 + kk * 32 + l4 * 8;
            async_copy16(&Bs[c * 512], sb);
        }
        __syncthreads();

#pragma unroll
        for (int kk = 0; kk < 2; ++kk) {
            bf16x8 af[4], bf[4];
#pragma unroll
            for (int mi = 0; mi < 4; ++mi)
                af[mi] = *reinterpret_cast<const bf16x8*>(&As[((wr * 4 + mi) * 2 + kk) * 512 + lane * 8]);
#pragma unroll
            for (int ni = 0; ni < 4; ++ni)
                bf[ni] = *reinterpret_cast<const bf16x8*>(&Bs[((wc * 4 + ni) * 2 + kk) * 512 + lane * 8]);
#pragma unroll
            for (int mi = 0; mi < 4; ++mi)
#pragma unroll
                for (int ni = 0; ni < 4; ++ni)
                    acc[mi][ni] = __builtin_amdgcn_mfma_f32_16x16x32_bf16(af[mi], bf[ni], acc[mi][ni], 0, 0, 0);
        }
        __syncthreads();
    }

    const float scl = (n0 < CDIM) ? SCALE : 1.0f;
    float bias[4];
#pragma unroll
    for (int ni = 0; ni < 4; ++ni)
        bias[ni] = bqkv[n0 + wc * 64 + ni * 16 + l15];

    __bf16* Cs = smem;   // [128][128] bf16, byte ^= ((row>>2)&3)<<5
#pragma unroll
    for (int mi = 0; mi < 4; ++mi)
#pragma unroll
        for (int ni = 0; ni < 4; ++ni)
#pragma unroll
            for (int r = 0; r < 4; ++r) {
                int row = wr * 64 + mi * 16 + l4 * 4 + r;
                int col = wc * 64 + ni * 16 + l15;
                int byte = (row * 256 + col * 2) ^ (((row >> 2) & 3) << 5);
                *reinterpret_cast<__bf16*>(reinterpret_cast<char*>(Cs) + byte) =
                    (__bf16)((acc[mi][ni][r] + bias[ni]) * scl);
            }
    __syncthreads();

#pragma unroll
    for (int it = 0; it < 8; ++it) {
        int idx = it * 4096 + tid * 16;
        int row = idx >> 8, bcol = idx & 255;
        int sb = (row * 256 + bcol) ^ (((row >> 2) & 3) << 5);
        uint4 v = *reinterpret_cast<const uint4*>(reinterpret_cast<const char*>(Cs) + sb);
        *reinterpret_cast<uint4*>(reinterpret_cast<char*>(&qkvb[(size_t)(bm0 + row) * NQKV + n0]) + bcol) = v;
    }
}

// ---------------- K2: attention (r7 structure + coalesced V staging) ----------------
// grid (B, 3): 256 thr = 4 waves; wave = one head. No barriers.
// V: 4 coalesced 16B loads/lane -> wave-private LDS [d][tok] (d-XOR swizzled) -> ds_read_b128 frags.

__global__ __launch_bounds__(256) void attn(
    const __bf16* __restrict__ qkvb, const float* __restrict__ addend,
    __bf16* __restrict__ attnout)
{
    __shared__ __attribute__((aligned(16))) __bf16 vt[4][32 * 64];    // [wave][d][tok ^ ((d&7)<<3)] 4KB/wave
    __shared__ __attribute__((aligned(16))) __bf16 ps[4][2][64][8];   // [wave][kb][lane][8]
    const int b = blockIdx.x;
    const int tid = threadIdx.x;
    const int wave = tid >> 6, lane = tid & 63;
    const int l15 = lane & 15, l4 = lane >> 4;
    const int h = blockIdx.y * 4 + wave;
    const int w = b & (NWIN - 1);

    const __bf16* base = qkvb + (size_t)b * NTOK * NQKV;

    // ---- stage V coalesced: lane loads v[tok][c8..c8+7], scatters transposed into vt ----
    {
        const int tokb = lane >> 2;         // 0..15
        const int c8   = (lane & 3) * 8;    // 0,8,16,24
#pragma unroll
        for (int i = 0; i < 4; ++i) {
            int tok = i * 16 + tokb;
            bf16x8 vv = *reinterpret_cast<const bf16x8*>(base + (size_t)tok * NQKV + 2 * CDIM + h * HD + c8);
#pragma unroll
            for (int j = 0; j < 8; ++j) {
                int d = c8 + j;
                vt[wave][d * 64 + (tok ^ ((d & 7) << 3))] = vv[j];
            }
        }
    }

    bf16x8 kf[4];
#pragma unroll
    for (int nt = 0; nt < 4; ++nt)
        kf[nt] = *reinterpret_cast<const bf16x8*>(base + (size_t)(nt * 16 + l15) * NQKV + CDIM + h * HD + l4 * 8);

    const float* add_h = addend + (size_t)(w * HEADS + h) * (NTOK * NTOK);

    for (int mt = 0; mt < 4; ++mt) {
        bf16x8 qf = *reinterpret_cast<const bf16x8*>(base + (size_t)(mt * 16 + l15) * NQKV + h * HD + l4 * 8);
        f32x4 s[4];
#pragma unroll
        for (int nt = 0; nt < 4; ++nt) {
            f32x4 z = {};
            s[nt] = __builtin_amdgcn_mfma_f32_16x16x32_bf16(qf, kf[nt], z, 0, 0, 0);
        }

#pragma unroll
        for (int r = 0; r < 4; ++r) {
            int m = mt * 16 + l4 * 4 + r;
            float vals[4];
#pragma unroll
            for (int nt = 0; nt < 4; ++nt) {
                int n = nt * 16 + l15;
                float sv = s[nt][r];
                if (n < NTOK) {
                    if (m < NTOK) sv += add_h[m * NTOK + n];
                } else {
                    sv = -1e30f;
                }
                vals[nt] = sv;
            }
            float mx = fmaxf(fmaxf(vals[0], vals[1]), fmaxf(vals[2], vals[3]));
            mx = fmaxf(mx, __shfl_xor(mx, 1));
            mx = fmaxf(mx, __shfl_xor(mx, 2));
            mx = fmaxf(mx, __shfl_xor(mx, 4));
            mx = fmaxf(mx, __shfl_xor(mx, 8));
            float e0 = __expf(vals[0] - mx);
            float e1 = __expf(vals[1] - mx);
            float e2 = __expf(vals[2] - mx);
            float e3 = __expf(vals[3] - mx);
            float sum = (e0 + e1) + (e2 + e3);
            sum += __shfl_xor(sum, 1);
            sum += __shfl_xor(sum, 2);
            sum += __shfl_xor(sum, 4);
            sum += __shfl_xor(sum, 8);
            float inv = 1.0f / sum;
            float ev[4] = {e0, e1, e2, e3};
#pragma unroll
            for (int nt = 0; nt < 4; ++nt) {
                int lp = (l4 * 4 + r) + 16 * ((nt & 1) * 2 + (l15 >> 3));
                ps[wave][nt >> 1][lp][l15 & 7] = (__bf16)(ev[nt] * inv);
            }
        }

        f32x4 o[2] = {};
#pragma unroll
        for (int kb = 0; kb < 2; ++kb) {
            bf16x8 ap = *reinterpret_cast<const bf16x8*>(&ps[wave][kb][lane][0]);
#pragma unroll
            for (int dt = 0; dt < 2; ++dt) {
                int d = dt * 16 + l15;
                bf16x8 bv = *reinterpret_cast<const bf16x8*>(
                    &vt[wave][d * 64 + ((kb * 32 + l4 * 8) ^ ((l15 & 7) << 3))]);
                o[dt] = __builtin_amdgcn_mfma_f32_16x16x32_bf16(ap, bv, o[dt], 0, 0, 0);
            }
        }
#pragma unroll
        for (int dt = 0; dt < 2; ++dt) {
            int col = h * HD + dt * 16 + l15;
#pragma unroll
            for (int r = 0; r < 4; ++r) {
                int tok = mt * 16 + l4 * 4 + r;
                if (tok < NTOK)
                    attnout[((size_t)b * NTOK + tok) * CDIM + col] = (__bf16)o[dt][r];
            }
        }
    }
}

// ---------------- K3: out projection (unchanged from r7) ----------------

__global__ __launch_bounds__(256, 3) void out_proj(
    const __bf16* __restrict__ A, const __bf16* __restrict__ WoutT,
    const float* __restrict__ bout, float* __restrict__ out)
{
    __shared__ __attribute__((aligned(16))) __bf16 as[4 * 12 * 512];   // frags [mt][kb][slot][8]
    const int blk = blockIdx.x, tid = threadIdx.x;
    const int wave = tid >> 6, lane = tid & 63;
    const int l15 = lane & 15, l4 = lane >> 4;

    const __bf16* Ab = A + (size_t)blk * 64 * CDIM;
    for (int i = tid; i < 64 * CDIM / 8; i += 256) {
        int4 ld = reinterpret_cast<const int4*>(Ab)[i];
        int e = i * 8;
        int row = e / CDIM, c = e % CDIM;
        int mt = row >> 4, kb = c >> 5;
        int lp = (row & 15) + 16 * ((c & 31) >> 3);
        int slot = lp ^ (kb & 7);
        *reinterpret_cast<int4*>(&as[((mt * 12 + kb) * 64 + slot) * 8]) = ld;
    }
    __syncthreads();

    f32x4 acc[6][4] = {};
    for (int kb = 0; kb < 12; ++kb) {
        int slot = lane ^ (kb & 7);
        bf16x8 af[4];
#pragma unroll
        for (int mt = 0; mt < 4; ++mt)
            af[mt] = *reinterpret_cast<const bf16x8*>(&as[((mt * 12 + kb) * 64 + slot) * 8]);
#pragma unroll
        for (int j = 0; j < 6; ++j) {
            int col = (wave * 6 + j) * 16 + l15;
            bf16x8 bf = *reinterpret_cast<const bf16x8*>(WoutT + (size_t)col * CDIM + kb * 32 + l4 * 8);
#pragma unroll
            for (int mt = 0; mt < 4; ++mt)
                acc[j][mt] = __builtin_amdgcn_mfma_f32_16x16x32_bf16(af[mt], bf, acc[j][mt], 0, 0, 0);
        }
    }
#pragma unroll
    for (int j = 0; j < 6; ++j) {
        int col = (wave * 6 + j) * 16 + l15;
        float bias = bout[col];
#pragma unroll
        for (int mt = 0; mt < 4; ++mt) {
#pragma unroll
            for (int r = 0; r < 4; ++r) {
                size_t row = (size_t)blk * 64 + mt * 16 + l4 * 4 + r;
                out[row * CDIM + col] = acc[j][mt][r] + bias;
            }
        }
    }
}

// ---------------- launch ----------------

extern "C" void kernel_launch(void* const* d_in, const int* in_sizes, int n_in,
                              void* d_out, int out_size, void* d_ws, size_t ws_size,
                              hipStream_t stream) {
    (void)n_in; (void)out_size; (void)ws_size;
    const float* x    = (const float*)d_in[0];
    const float* mask = (const float*)d_in[1];
    const float* Wqkv = (const float*)d_in[2];
    const float* bqkv = (const float*)d_in[3];
    const float* Wout = (const float*)d_in[4];
    const float* bout = (const float*)d_in[5];
    const float* rpb  = (const float*)d_in[6];
    const int*   rel  = (const int*)d_in[7];

    const int B = in_sizes[0] / (NTOK * CDIM);   // 4096
    const int M = B * NTOK;                      // 200704

    char* ws = (char*)d_ws;
    __bf16* WqkvT   = (__bf16*)(ws + OFF_WQKVT);
    __bf16* WoutT   = (__bf16*)(ws + OFF_WOUTT);
    float*  addend  = (float*)(ws + OFF_ADDEND);
    __bf16* qkvb    = (__bf16*)(ws + OFF_QKVB);
    __bf16* xb      = (__bf16*)(ws + OFF_XB);       // aliases attnout (xb dead before attn writes)
    __bf16* attnout = (__bf16*)(ws + OFF_ATTNOUT);
    float*  out     = (float*)d_out;

    prep_weights<<<(NQKV * CDIM + 255) / 256, 256, 0, stream>>>(Wqkv, Wout, WqkvT, WoutT);
    prep_addend<<<(NWIN * HEADS * NTOK * NTOK + 255) / 256, 256, 0, stream>>>(rpb, rel, mask, addend);
    prep_xb<<<2048, 256, 0, stream>>>(x, xb, M * CDIM / 8);
    gemm_qkv<<<(M / 128) * (NQKV / 128), 256, 0, stream>>>(xb, WqkvT, bqkv, qkvb);
    attn<<<dim3(B, 3), 256, 0, stream>>>(qkvb, addend, attnout);
    out_proj<<<M / 64, 256, 0, stream>>>(attnout, WoutT, bout, out);
}